// Round 1
// baseline (10252.747 us; speedup 1.0000x reference)
//
#include <hip/hip_runtime.h>
#include <math.h>

#define HEADS 12
#define DH 64
#define DD 768
#define FFD 3072
#define EMBD 300
#define NLAYER 4
#define NB 16

// ---------------- block reduction ----------------
template<bool ISMAX>
__device__ __forceinline__ float block_reduce(float v, float* red) {
  #pragma unroll
  for (int o = 32; o; o >>= 1) {
    float t = __shfl_xor(v, o);
    v = ISMAX ? fmaxf(v, t) : (v + t);
  }
  const int wid = threadIdx.x >> 6;
  const int nw = blockDim.x >> 6;
  __syncthreads();
  if ((threadIdx.x & 63) == 0) red[wid] = v;
  __syncthreads();
  float r = red[0];
  for (int w = 1; w < nw; ++w) r = ISMAX ? fmaxf(r, red[w]) : (r + red[w]);
  return r;
}

// ---------------- GEMM: C[N,M] = act(A[N,K] @ W[K,M] + bias) ----------------
#define BM 128
#define BN 128
#define BK 16

template<int ACT>
__launch_bounds__(256)
__global__ void gemm_kernel(const float* __restrict__ A, const float* __restrict__ W,
                            const float* __restrict__ bias, float* __restrict__ C,
                            int K, int M) {
  __shared__ __align__(16) float As[BK][BM + 4];
  __shared__ __align__(16) float Ws[BK][BN + 4];
  const int bm = blockIdx.x * BM;
  const int bn = blockIdx.y * BN;
  const int tid = threadIdx.x;
  const int tx = tid & 15;
  const int ty = tid >> 4;
  float acc[8][8];
  #pragma unroll
  for (int i = 0; i < 8; ++i)
    #pragma unroll
    for (int j = 0; j < 8; ++j) acc[i][j] = 0.f;

  for (int k0 = 0; k0 < K; k0 += BK) {
    #pragma unroll
    for (int tld = 0; tld < 2; ++tld) {
      const int vv = tid + (tld << 8);
      {
        const int r = vv >> 2, c4 = (vv & 3) << 2;
        const float4 a = *reinterpret_cast<const float4*>(&A[(size_t)(bm + r) * K + k0 + c4]);
        As[c4 + 0][r] = a.x; As[c4 + 1][r] = a.y; As[c4 + 2][r] = a.z; As[c4 + 3][r] = a.w;
      }
      {
        const int r = vv >> 5, c4 = (vv & 31) << 2;
        *reinterpret_cast<float4*>(&Ws[r][c4]) =
            *reinterpret_cast<const float4*>(&W[(size_t)(k0 + r) * M + bn + c4]);
      }
    }
    __syncthreads();
    #pragma unroll
    for (int kq = 0; kq < BK; ++kq) {
      float a[8], w[8];
      *reinterpret_cast<float4*>(&a[0]) = *reinterpret_cast<const float4*>(&As[kq][ty * 8]);
      *reinterpret_cast<float4*>(&a[4]) = *reinterpret_cast<const float4*>(&As[kq][ty * 8 + 4]);
      *reinterpret_cast<float4*>(&w[0]) = *reinterpret_cast<const float4*>(&Ws[kq][tx * 8]);
      *reinterpret_cast<float4*>(&w[4]) = *reinterpret_cast<const float4*>(&Ws[kq][tx * 8 + 4]);
      #pragma unroll
      for (int i = 0; i < 8; ++i)
        #pragma unroll
        for (int j = 0; j < 8; ++j)
          acc[i][j] = fmaf(a[i], w[j], acc[i][j]);
    }
    __syncthreads();
  }
  #pragma unroll
  for (int i = 0; i < 8; ++i) {
    const size_t row = (size_t)(bm + ty * 8 + i) * M + bn + tx * 8;
    float o[8];
    #pragma unroll
    for (int j = 0; j < 8; ++j) {
      float v = acc[i][j] + bias[bn + tx * 8 + j];
      if (ACT == 1) {
        const float u = 0.7978845608028654f * (v + 0.044715f * v * v * v);
        v = 0.5f * v * (1.f + tanhf(u));
      }
      o[j] = v;
    }
    *reinterpret_cast<float4*>(&C[row]) = *reinterpret_cast<const float4*>(&o[0]);
    *reinterpret_cast<float4*>(&C[row + 4]) = *reinterpret_cast<const float4*>(&o[4]);
  }
}

// ---------------- fc1 + pos_emb + LayerNorm ----------------
__launch_bounds__(256)
__global__ void fc1_ln_kernel(const float* __restrict__ x, const float* __restrict__ W,
                              const float* __restrict__ bb, const float* __restrict__ pos,
                              const float* __restrict__ g, const float* __restrict__ be,
                              float* __restrict__ out, int S) {
  __shared__ float xs[EMBD];
  __shared__ float red[4];
  const int tok = blockIdx.x;
  const int spos = tok % S;
  for (int i = threadIdx.x; i < EMBD; i += 256) xs[i] = x[(size_t)tok * EMBD + i];
  __syncthreads();
  float y[3]; float s = 0.f, ss = 0.f;
  #pragma unroll
  for (int i = 0; i < 3; ++i) {
    const int j = threadIdx.x + (i << 8);
    float a = bb[j] + pos[(size_t)spos * DD + j];
    for (int kq = 0; kq < EMBD; ++kq)
      a = fmaf(xs[kq], W[(size_t)kq * DD + j], a);
    y[i] = a; s += a; ss += a * a;
  }
  s = block_reduce<false>(s, red);
  ss = block_reduce<false>(ss, red);
  const float mean = s * (1.f / DD);
  const float var = ss * (1.f / DD) - mean * mean;
  const float inv = rsqrtf(var + 1e-12f);
  #pragma unroll
  for (int i = 0; i < 3; ++i) {
    const int j = threadIdx.x + (i << 8);
    out[(size_t)tok * DD + j] = (y[i] - mean) * inv * g[j] + be[j];
  }
}

// ---------------- attention: per (b,h), block = S threads ----------------
#define QROWS 16
__global__ void attn_kernel(const float* __restrict__ q, const float* __restrict__ kk_,
                            const float* __restrict__ vv, float* __restrict__ o, int S) {
  const int b = blockIdx.x / HEADS;
  const int h = blockIdx.x % HEADS;
  const int t = threadIdx.x;
  const int nch = blockDim.x >> 6;
  __shared__ __align__(16) float qs[DH];
  __shared__ float ps[256];
  __shared__ float red[4];
  __shared__ float part[4][DH];
  const size_t hb = (size_t)(b * S) * DD + (size_t)h * DH;
  const float* krow = kk_ + hb + (size_t)t * DD;
  const int q_end = blockIdx.y * QROWS + QROWS;
  for (int qi = blockIdx.y * QROWS; qi < q_end; ++qi) {
    if (t < DH) qs[t] = q[hb + (size_t)qi * DD + t];
    __syncthreads();
    float sc = 0.f;
    #pragma unroll
    for (int d4 = 0; d4 < DH; d4 += 4) {
      const float4 kv = *reinterpret_cast<const float4*>(krow + d4);
      const float4 qv = *reinterpret_cast<const float4*>(&qs[d4]);
      sc += qv.x * kv.x + qv.y * kv.y + qv.z * kv.z + qv.w * kv.w;
    }
    sc *= 0.125f;
    const float m = block_reduce<true>(sc, red);
    const float p = __expf(sc - m);
    const float Z = block_reduce<false>(p, red);
    ps[t] = p / Z;
    __syncthreads();
    const int d = t & (DH - 1);
    const int c = t >> 6;
    float acc = 0.f;
    for (int s2 = c; s2 < S; s2 += nch)
      acc = fmaf(ps[s2], vv[hb + (size_t)s2 * DD + d], acc);
    part[c][d] = acc;
    __syncthreads();
    if (t < DH) {
      float r = part[0][t];
      for (int cc = 1; cc < nch; ++cc) r += part[cc][t];
      o[hb + (size_t)qi * DD + t] = r;
    }
    __syncthreads();
  }
}

// ---------------- residual add + LayerNorm ----------------
__launch_bounds__(256)
__global__ void add_ln_kernel(const float* __restrict__ hin, const float* __restrict__ dlt,
                              const float* __restrict__ g, const float* __restrict__ be,
                              float* __restrict__ out) {
  __shared__ float red[4];
  const size_t row = (size_t)blockIdx.x * DD;
  float x[3]; float s = 0.f, ss = 0.f;
  #pragma unroll
  for (int i = 0; i < 3; ++i) {
    const int j = threadIdx.x + (i << 8);
    x[i] = hin[row + j] + dlt[row + j];
    s += x[i]; ss += x[i] * x[i];
  }
  s = block_reduce<false>(s, red);
  ss = block_reduce<false>(ss, red);
  const float mean = s * (1.f / DD);
  const float var = ss * (1.f / DD) - mean * mean;
  const float inv = rsqrtf(var + 1e-12f);
  #pragma unroll
  for (int i = 0; i < 3; ++i) {
    const int j = threadIdx.x + (i << 8);
    out[row + j] = (x[i] - mean) * inv * g[j] + be[j];
  }
}

// ---------------- final cosine reduction ----------------
struct Outs4 { const float* p[4]; };

__launch_bounds__(256)
__global__ void invnorm_kernel(Outs4 o4, float* __restrict__ invn) {
  __shared__ float red[4];
  const size_t row = (size_t)blockIdx.x * DD;
  float ss = 0.f;
  #pragma unroll
  for (int l = 0; l < 4; ++l)
    #pragma unroll
    for (int i = 0; i < 3; ++i) {
      const float v = o4.p[l][row + threadIdx.x + (i << 8)];
      ss += v * v;
    }
  ss = block_reduce<false>(ss, red);
  if (threadIdx.x == 0) invn[blockIdx.x] = 1.f / fmaxf(sqrtf(ss), 1e-8f);
}

__launch_bounds__(256)
__global__ void normsum_kernel(Outs4 o4, const float* __restrict__ invn,
                               float* __restrict__ acc, int S) {
  const int b = blockIdx.x;
  const int l = blockIdx.y / 3;
  const int j = (blockIdx.y % 3) * 256 + threadIdx.x;
  const float* __restrict__ src = o4.p[l];
  float s = 0.f;
  const size_t base = (size_t)b * S;
  for (int si = 0; si < S; ++si)
    s = fmaf(src[(base + si) * DD + j], invn[base + si], s);
  acc[(size_t)b * (4 * DD) + (size_t)l * DD + j] = s;
}

__launch_bounds__(256)
__global__ void final_dot_kernel(const float* __restrict__ a, const float* __restrict__ c,
                                 float* __restrict__ out) {
  __shared__ float red[4];
  const size_t base = (size_t)blockIdx.x * (4 * DD);
  float s = 0.f;
  #pragma unroll
  for (int i = 0; i < 12; ++i) {
    const int j = threadIdx.x + (i << 8);
    s = fmaf(a[base + j], c[base + j], s);
  }
  s = block_reduce<false>(s, red);
  if (threadIdx.x == 0) out[blockIdx.x] = s;
}

// ---------------- host orchestration ----------------
extern "C" void kernel_launch(void* const* d_in, const int* in_sizes, int n_in,
                              void* d_out, int out_size, void* d_ws, size_t ws_size,
                              hipStream_t stream) {
  (void)in_sizes; (void)n_in; (void)out_size; (void)ws_size;
  const float* ctx   = (const float*)d_in[0];
  const float* asp   = (const float*)d_in[1];
  const float* fc1_w = (const float*)d_in[2];
  const float* fc1_b = (const float*)d_in[3];
  const float* pos   = (const float*)d_in[4];
  const float* emb_g = (const float*)d_in[5];
  const float* emb_b = (const float*)d_in[6];
  const float* Wq    = (const float*)d_in[7];
  const float* bq    = (const float*)d_in[8];
  const float* Wk    = (const float*)d_in[9];
  const float* bk    = (const float*)d_in[10];
  const float* Wv    = (const float*)d_in[11];
  const float* bv    = (const float*)d_in[12];
  const float* Wo    = (const float*)d_in[13];
  const float* bo    = (const float*)d_in[14];
  const float* ln1g  = (const float*)d_in[15];
  const float* ln1b  = (const float*)d_in[16];
  const float* W1    = (const float*)d_in[17];
  const float* bf1   = (const float*)d_in[18];
  const float* W2    = (const float*)d_in[19];
  const float* bf2   = (const float*)d_in[20];
  const float* ln2g  = (const float*)d_in[21];
  const float* ln2b  = (const float*)d_in[22];
  float* out = (float*)d_out;

  float* ws = (float*)d_ws;
  const size_t NcD = (size_t)NB * 256 * DD;   // max tokens (ctx) * D
  size_t off = 0;
  float* h0   = ws + off; off += NcD;
  float* o0   = ws + off; off += NcD;
  float* o1   = ws + off; off += NcD;
  float* o2   = ws + off; off += NcD;
  float* o3   = ws + off; off += NcD;
  float* hm   = ws + off; off += NcD;
  float* tmp  = ws + off; off += NcD;
  float* mid  = ws + off; off += 4 * NcD;     // also hosts q,k,v,ao
  float* accC = ws + off; off += (size_t)NB * 4 * DD;
  float* accA = ws + off; off += (size_t)NB * 4 * DD;
  float* invn = ws + off; off += (size_t)NB * 256;

  float* outs[4] = {o0, o1, o2, o3};

  for (int pass = 0; pass < 2; ++pass) {
    const int S = (pass == 0) ? 256 : 128;
    const float* x = (pass == 0) ? ctx : asp;
    float* acc = (pass == 0) ? accC : accA;
    const int N = NB * S;

    fc1_ln_kernel<<<N, 256, 0, stream>>>(x, fc1_w, fc1_b, pos, emb_g, emb_b, h0, S);

    const float* hin = h0;
    float* qb = mid;
    float* kb = mid + NcD;
    float* vb = mid + 2 * NcD;
    float* ao = mid + 3 * NcD;

    for (int l = 0; l < NLAYER; ++l) {
      const dim3 gD(N / BM, DD / BN);
      gemm_kernel<0><<<gD, 256, 0, stream>>>(hin, Wq + (size_t)l * DD * DD, bq + l * DD, qb, DD, DD);
      gemm_kernel<0><<<gD, 256, 0, stream>>>(hin, Wk + (size_t)l * DD * DD, bk + l * DD, kb, DD, DD);
      gemm_kernel<0><<<gD, 256, 0, stream>>>(hin, Wv + (size_t)l * DD * DD, bv + l * DD, vb, DD, DD);
      attn_kernel<<<dim3(NB * HEADS, S / QROWS), S, 0, stream>>>(qb, kb, vb, ao, S);
      gemm_kernel<0><<<gD, 256, 0, stream>>>(ao, Wo + (size_t)l * DD * DD, bo + l * DD, tmp, DD, DD);
      add_ln_kernel<<<N, 256, 0, stream>>>(hin, tmp, ln1g + l * DD, ln1b + l * DD, hm);
      gemm_kernel<1><<<dim3(N / BM, FFD / BN), 256, 0, stream>>>(hm, W1 + (size_t)l * DD * FFD, bf1 + l * FFD, mid, DD, FFD);
      gemm_kernel<0><<<gD, 256, 0, stream>>>(mid, W2 + (size_t)l * FFD * DD, bf2 + l * DD, tmp, FFD, DD);
      add_ln_kernel<<<N, 256, 0, stream>>>(hm, tmp, ln2g + l * DD, ln2b + l * DD, outs[l]);
      hin = outs[l];
    }

    Outs4 o4;
    for (int i = 0; i < 4; ++i) o4.p[i] = outs[i];
    invnorm_kernel<<<N, 256, 0, stream>>>(o4, invn);
    normsum_kernel<<<dim3(NB, 12), 256, 0, stream>>>(o4, invn, acc, S);
  }

  final_dot_kernel<<<NB, 256, 0, stream>>>(accA, accC, out);
}

// Round 2
// 1675.987 us; speedup vs baseline: 6.1174x; 6.1174x over previous
//
#include <hip/hip_runtime.h>
#include <math.h>

typedef _Float16 f16;
typedef _Float16 h8 __attribute__((ext_vector_type(8)));
typedef float f32x4 __attribute__((ext_vector_type(4)));

#define HEADS 12
#define DH 64
#define DD 768
#define FFD 3072
#define EMBD 300
#define KPAD 320
#define NLAYER 4
#define NB 16

// ---------------- block reduction (sum) ----------------
__device__ __forceinline__ float block_reduce_sum(float v, float* red) {
  #pragma unroll
  for (int o = 32; o; o >>= 1) v += __shfl_xor(v, o);
  const int wid = threadIdx.x >> 6;
  __syncthreads();
  if ((threadIdx.x & 63) == 0) red[wid] = v;
  __syncthreads();
  float r = red[0];
  #pragma unroll
  for (int w = 1; w < 4; ++w) r += red[w];
  return r;
}

// ---------------- weight transpose + cast: W[K][M] f32 -> Wt[M][Kpad] f16 ----------------
__launch_bounds__(256)
__global__ void transpose_cast_kernel(const float* __restrict__ W, f16* __restrict__ Wt,
                                      int K, int M, int Kpad) {
  __shared__ float t[32][33];
  const int k0 = blockIdx.x * 32, m0 = blockIdx.y * 32;
  const int c = threadIdx.x & 31, r8 = threadIdx.x >> 5;
  #pragma unroll
  for (int p = 0; p < 4; ++p) {
    const int k = k0 + r8 + p * 8;
    t[r8 + p * 8][c] = (k < K && m0 + c < M) ? W[(size_t)k * M + m0 + c] : 0.f;
  }
  __syncthreads();
  #pragma unroll
  for (int p = 0; p < 4; ++p) {
    const int m = m0 + r8 + p * 8;
    const int k = k0 + c;
    if (m < M && k < Kpad) Wt[(size_t)m * Kpad + k] = (f16)t[c][r8 + p * 8];
  }
}

__launch_bounds__(256)
__global__ void castpad_kernel(const float* __restrict__ x, f16* __restrict__ xp) {
  const int tok = blockIdx.x;
  for (int j = threadIdx.x; j < KPAD; j += 256)
    xp[(size_t)tok * KPAD + j] = (j < EMBD) ? (f16)x[(size_t)tok * EMBD + j] : (f16)0.f;
}

__launch_bounds__(256)
__global__ void bias_concat_kernel(const float* __restrict__ bq, const float* __restrict__ bk,
                                   const float* __restrict__ bv, float* __restrict__ bqkv) {
  const int l = blockIdx.x;
  for (int j = threadIdx.x; j < DD; j += 256) {
    bqkv[l * 3 * DD + j] = bq[l * DD + j];
    bqkv[l * 3 * DD + DD + j] = bk[l * DD + j];
    bqkv[l * 3 * DD + 2 * DD + j] = bv[l * DD + j];
  }
}

// ---------------- f16 MFMA GEMM: C[N,M] = act(A[N,K] @ Bt[M,K]^T + bias) ----------------
#define GBM 128
#define GBN 128
#define GBK 32

template<int ACT, int OUTF16>
__launch_bounds__(256)
__global__ void gemm_f16(const f16* __restrict__ A, const f16* __restrict__ Bt,
                         const float* __restrict__ bias,
                         float* __restrict__ C32, f16* __restrict__ C16,
                         int K, int M) {
  __shared__ __align__(16) f16 As[GBM][GBK + 8];
  __shared__ __align__(16) f16 Bs[GBN][GBK + 8];
  const int tid = threadIdx.x;
  const int lane = tid & 63, wid = tid >> 6;
  const int wr = (wid >> 1) * 64, wc = (wid & 1) * 64;
  const int bm = blockIdx.x * GBM, bn = blockIdx.y * GBN;
  const int l15 = lane & 15, lg = lane >> 4;
  f32x4 acc[4][4] = {};

  for (int k0 = 0; k0 < K; k0 += GBK) {
    h8 av[2], bv_[2];
    #pragma unroll
    for (int s = 0; s < 2; ++s) {
      const int c = tid + (s << 8);
      const int row = c >> 2, seg = c & 3;
      av[s]  = *(const h8*)&A[(size_t)(bm + row) * K + k0 + seg * 8];
      bv_[s] = *(const h8*)&Bt[(size_t)(bn + row) * K + k0 + seg * 8];
    }
    __syncthreads();
    #pragma unroll
    for (int s = 0; s < 2; ++s) {
      const int c = tid + (s << 8);
      const int row = c >> 2, seg = c & 3;
      *(h8*)&As[row][seg * 8] = av[s];
      *(h8*)&Bs[row][seg * 8] = bv_[s];
    }
    __syncthreads();
    h8 af[4], bf[4];
    #pragma unroll
    for (int m = 0; m < 4; ++m) af[m] = *(const h8*)&As[wr + m * 16 + l15][lg * 8];
    #pragma unroll
    for (int n = 0; n < 4; ++n) bf[n] = *(const h8*)&Bs[wc + n * 16 + l15][lg * 8];
    #pragma unroll
    for (int m = 0; m < 4; ++m)
      #pragma unroll
      for (int n = 0; n < 4; ++n)
        acc[m][n] = __builtin_amdgcn_mfma_f32_16x16x32_f16(af[m], bf[n], acc[m][n], 0, 0, 0);
  }

  #pragma unroll
  for (int m = 0; m < 4; ++m) {
    #pragma unroll
    for (int n = 0; n < 4; ++n) {
      #pragma unroll
      for (int r = 0; r < 4; ++r) {
        const int row = bm + wr + m * 16 + lg * 4 + r;
        const int col = bn + wc + n * 16 + l15;
        float v = acc[m][n][r] + bias[col];
        if (ACT == 1) {
          const float u = 0.7978845608028654f * (v + 0.044715f * v * v * v);
          v = 0.5f * v * (1.f + tanhf(u));
        }
        if (OUTF16) C16[(size_t)row * M + col] = (f16)v;
        else        C32[(size_t)row * M + col] = v;
      }
    }
  }
}

// ---------------- MFMA flash attention: one block per (b,h) ----------------
template<int S>
__launch_bounds__(256)
__global__ void attn_mfma_kernel(const f16* __restrict__ qkv, f16* __restrict__ ao) {
  constexpr int KSTR = 88;    // Ks row stride (f16): 176B, 16B-aligned, 2-way banks
  constexpr int VSTR = 264;   // Vt/P row stride: 528B
  __shared__ __align__(16) f16 Ks[S][KSTR];
  __shared__ __align__(16) f16 Vt[DH][VSTR];
  __shared__ __align__(16) f16 Pl[4][16][VSTR];
  const int b = blockIdx.x / HEADS, h = blockIdx.x % HEADS;
  const int tid = threadIdx.x, lane = tid & 63, wid = tid >> 6;
  const int l15 = lane & 15, lg = lane >> 4;
  const size_t base = (size_t)(b * S) * (3 * DD) + (size_t)h * DH;
  const f16* qg = qkv + base;
  const f16* kg = qkv + base + DD;
  const f16* vg = qkv + base + 2 * DD;

  // stage K rows and V^T
  for (int c = tid; c < S * 8; c += 256) {
    const int row = c >> 3, off = (c & 7) * 8;
    *(h8*)&Ks[row][off] = *(const h8*)&kg[(size_t)row * (3 * DD) + off];
    const h8 vv = *(const h8*)&vg[(size_t)row * (3 * DD) + off];
    #pragma unroll
    for (int j = 0; j < 8; ++j) Vt[off + j][row] = vv[j];
  }
  __syncthreads();

  for (int qt = wid; qt < S / 16; qt += 4) {
    const int q0 = qt * 16;
    h8 aq[2];
    #pragma unroll
    for (int s = 0; s < 2; ++s)
      aq[s] = *(const h8*)&qg[(size_t)(q0 + l15) * (3 * DD) + s * 32 + lg * 8];

    f32x4 sc[S / 16];
    #pragma unroll
    for (int kt = 0; kt < S / 16; ++kt) {
      f32x4 c = {};
      const h8 b0 = *(const h8*)&Ks[kt * 16 + l15][lg * 8];
      const h8 b1 = *(const h8*)&Ks[kt * 16 + l15][32 + lg * 8];
      c = __builtin_amdgcn_mfma_f32_16x16x32_f16(aq[0], b0, c, 0, 0, 0);
      c = __builtin_amdgcn_mfma_f32_16x16x32_f16(aq[1], b1, c, 0, 0, 0);
      sc[kt] = c;
    }
    // row softmax: rows q = lg*4 + r, cols spread over lanes (l15) and tiles
    float mx[4], zz[4];
    #pragma unroll
    for (int r = 0; r < 4; ++r) {
      float m = -1e30f;
      #pragma unroll
      for (int kt = 0; kt < S / 16; ++kt) m = fmaxf(m, sc[kt][r]);
      #pragma unroll
      for (int o = 1; o < 16; o <<= 1) m = fmaxf(m, __shfl_xor(m, o));
      mx[r] = m;
      zz[r] = 0.f;
    }
    #pragma unroll
    for (int kt = 0; kt < S / 16; ++kt)
      #pragma unroll
      for (int r = 0; r < 4; ++r) {
        const float p = __expf((sc[kt][r] - mx[r]) * 0.125f);
        zz[r] += p;
        Pl[wid][lg * 4 + r][kt * 16 + l15] = (f16)p;
      }
    #pragma unroll
    for (int r = 0; r < 4; ++r) {
      #pragma unroll
      for (int o = 1; o < 16; o <<= 1) zz[r] += __shfl_xor(zz[r], o);
      zz[r] = 1.f / zz[r];
    }
    __syncthreads();
    // PV
    f32x4 o4[4] = {};
    #pragma unroll
    for (int ks = 0; ks < S / 32; ++ks) {
      const h8 pa = *(const h8*)&Pl[wid][l15][ks * 32 + lg * 8];
      #pragma unroll
      for (int n = 0; n < 4; ++n) {
        const h8 bv_ = *(const h8*)&Vt[n * 16 + l15][ks * 32 + lg * 8];
        o4[n] = __builtin_amdgcn_mfma_f32_16x16x32_f16(pa, bv_, o4[n], 0, 0, 0);
      }
    }
    #pragma unroll
    for (int n = 0; n < 4; ++n)
      #pragma unroll
      for (int r = 0; r < 4; ++r) {
        const int row = q0 + lg * 4 + r;
        ao[(size_t)(b * S + row) * DD + h * DH + n * 16 + l15] = (f16)(o4[n][r] * zz[r]);
      }
    __syncthreads();
  }
}

// ---------------- fc1-out + pos_emb + LN -> f32 + f16 ----------------
__launch_bounds__(256)
__global__ void pos_ln_kernel(const float* __restrict__ tmp, const float* __restrict__ pos,
                              const float* __restrict__ g, const float* __restrict__ be,
                              float* __restrict__ of32, f16* __restrict__ of16, int S) {
  __shared__ float red[4];
  const int tok = blockIdx.x;
  const int s = tok % S;
  const size_t row = (size_t)tok * DD;
  float x[3]; float sm = 0.f, ss = 0.f;
  #pragma unroll
  for (int i = 0; i < 3; ++i) {
    const int j = threadIdx.x + (i << 8);
    x[i] = tmp[row + j] + pos[(size_t)s * DD + j];
    sm += x[i]; ss += x[i] * x[i];
  }
  sm = block_reduce_sum(sm, red);
  ss = block_reduce_sum(ss, red);
  const float mean = sm * (1.f / DD);
  const float inv = rsqrtf(ss * (1.f / DD) - mean * mean + 1e-12f);
  #pragma unroll
  for (int i = 0; i < 3; ++i) {
    const int j = threadIdx.x + (i << 8);
    const float v = (x[i] - mean) * inv * g[j] + be[j];
    of32[row + j] = v;
    of16[row + j] = (f16)v;
  }
}

// ---------------- residual add + LN -> f32 + f16 ----------------
__launch_bounds__(256)
__global__ void add_ln_dual(const float* __restrict__ hin, const float* __restrict__ dlt,
                            const float* __restrict__ g, const float* __restrict__ be,
                            float* __restrict__ of32, f16* __restrict__ of16) {
  __shared__ float red[4];
  const size_t row = (size_t)blockIdx.x * DD;
  float x[3]; float sm = 0.f, ss = 0.f;
  #pragma unroll
  for (int i = 0; i < 3; ++i) {
    const int j = threadIdx.x + (i << 8);
    x[i] = hin[row + j] + dlt[row + j];
    sm += x[i]; ss += x[i] * x[i];
  }
  sm = block_reduce_sum(sm, red);
  ss = block_reduce_sum(ss, red);
  const float mean = sm * (1.f / DD);
  const float inv = rsqrtf(ss * (1.f / DD) - mean * mean + 1e-12f);
  #pragma unroll
  for (int i = 0; i < 3; ++i) {
    const int j = threadIdx.x + (i << 8);
    const float v = (x[i] - mean) * inv * g[j] + be[j];
    of32[row + j] = v;
    of16[row + j] = (f16)v;
  }
}

// ---------------- final cosine reduction (f16 hidden states) ----------------
struct OutsF16 { const f16* p[4]; };

__launch_bounds__(256)
__global__ void invnorm16_kernel(OutsF16 o4, float* __restrict__ invn) {
  __shared__ float red[4];
  const size_t row = (size_t)blockIdx.x * DD;
  float ss = 0.f;
  #pragma unroll
  for (int l = 0; l < 4; ++l)
    #pragma unroll
    for (int i = 0; i < 3; ++i) {
      const float v = (float)o4.p[l][row + threadIdx.x + (i << 8)];
      ss += v * v;
    }
  ss = block_reduce_sum(ss, red);
  if (threadIdx.x == 0) invn[blockIdx.x] = 1.f / fmaxf(sqrtf(ss), 1e-8f);
}

__launch_bounds__(256)
__global__ void normsum16_kernel(OutsF16 o4, const float* __restrict__ invn,
                                 float* __restrict__ acc, int S) {
  const int b = blockIdx.x;
  const int l = blockIdx.y / 3;
  const int j = (blockIdx.y % 3) * 256 + threadIdx.x;
  const f16* __restrict__ src = o4.p[l];
  float s = 0.f;
  const size_t base = (size_t)b * S;
  for (int si = 0; si < S; ++si)
    s = fmaf((float)src[(base + si) * DD + j], invn[base + si], s);
  acc[(size_t)b * (4 * DD) + (size_t)l * DD + j] = s;
}

__launch_bounds__(256)
__global__ void final_dot_kernel(const float* __restrict__ a, const float* __restrict__ c,
                                 float* __restrict__ out) {
  __shared__ float red[4];
  const size_t base = (size_t)blockIdx.x * (4 * DD);
  float s = 0.f;
  #pragma unroll
  for (int i = 0; i < 12; ++i) {
    const int j = threadIdx.x + (i << 8);
    s = fmaf(a[base + j], c[base + j], s);
  }
  s = block_reduce_sum(s, red);
  if (threadIdx.x == 0) out[blockIdx.x] = s;
}

// ---------------- host orchestration ----------------
extern "C" void kernel_launch(void* const* d_in, const int* in_sizes, int n_in,
                              void* d_out, int out_size, void* d_ws, size_t ws_size,
                              hipStream_t stream) {
  (void)in_sizes; (void)n_in; (void)out_size; (void)ws_size;
  const float* ctx   = (const float*)d_in[0];
  const float* asp   = (const float*)d_in[1];
  const float* fc1_w = (const float*)d_in[2];
  const float* fc1_b = (const float*)d_in[3];
  const float* pos   = (const float*)d_in[4];
  const float* emb_g = (const float*)d_in[5];
  const float* emb_b = (const float*)d_in[6];
  const float* Wq    = (const float*)d_in[7];
  const float* bq    = (const float*)d_in[8];
  const float* Wk    = (const float*)d_in[9];
  const float* bk    = (const float*)d_in[10];
  const float* Wv    = (const float*)d_in[11];
  const float* bv    = (const float*)d_in[12];
  const float* Wo    = (const float*)d_in[13];
  const float* bo    = (const float*)d_in[14];
  const float* ln1g  = (const float*)d_in[15];
  const float* ln1b  = (const float*)d_in[16];
  const float* W1    = (const float*)d_in[17];
  const float* bf1   = (const float*)d_in[18];
  const float* W2    = (const float*)d_in[19];
  const float* bf2   = (const float*)d_in[20];
  const float* ln2g  = (const float*)d_in[21];
  const float* ln2b  = (const float*)d_in[22];
  float* out = (float*)d_out;

  // ---- workspace carving: f16 region then f32 region ----
  f16* f = (f16*)d_ws;
  size_t o = 0;
  f16* fc1T  = f + o; o += (size_t)DD * KPAD;
  f16* WqkvT = f + o; o += (size_t)NLAYER * 3 * DD * DD;
  f16* WoT   = f + o; o += (size_t)NLAYER * DD * DD;
  f16* W1T   = f + o; o += (size_t)NLAYER * FFD * DD;
  f16* W2T   = f + o; o += (size_t)NLAYER * DD * FFD;
  f16* R     = f + o; o += (size_t)4096 * FFD;   // alias: xpad | qkv+ao | mid
  f16* h0f16 = f + o; o += (size_t)4096 * DD;
  f16* hmf16 = f + o; o += (size_t)4096 * DD;
  f16* outs16[4];
  for (int l = 0; l < 4; ++l) { outs16[l] = f + o; o += (size_t)4096 * DD; }

  f16* xpad = R;
  f16* qkv  = R;
  f16* ao   = R + (size_t)4096 * 3 * DD;
  f16* mid  = R;

  float* g32 = (float*)(f + o);
  size_t o2 = 0;
  float* tmp     = g32 + o2; o2 += (size_t)4096 * DD;
  float* hmf32   = g32 + o2; o2 += (size_t)4096 * DD;
  float* houtf32 = g32 + o2; o2 += (size_t)4096 * DD;
  float* bqkv    = g32 + o2; o2 += (size_t)NLAYER * 3 * DD;
  float* accC    = g32 + o2; o2 += (size_t)NB * 4 * DD;
  float* accA    = g32 + o2; o2 += (size_t)NB * 4 * DD;
  float* invn    = g32 + o2; o2 += 4096;

  // ---- weight prep ----
  transpose_cast_kernel<<<dim3(KPAD / 32, DD / 32), 256, 0, stream>>>(fc1_w, fc1T, EMBD, DD, KPAD);
  for (int l = 0; l < NLAYER; ++l) {
    const size_t wd = (size_t)l * DD * DD;
    transpose_cast_kernel<<<dim3(DD / 32, DD / 32), 256, 0, stream>>>(Wq + wd, WqkvT + (size_t)l * 3 * DD * DD, DD, DD, DD);
    transpose_cast_kernel<<<dim3(DD / 32, DD / 32), 256, 0, stream>>>(Wk + wd, WqkvT + (size_t)l * 3 * DD * DD + (size_t)DD * DD, DD, DD, DD);
    transpose_cast_kernel<<<dim3(DD / 32, DD / 32), 256, 0, stream>>>(Wv + wd, WqkvT + (size_t)l * 3 * DD * DD + (size_t)2 * DD * DD, DD, DD, DD);
    transpose_cast_kernel<<<dim3(DD / 32, DD / 32), 256, 0, stream>>>(Wo + wd, WoT + wd, DD, DD, DD);
    transpose_cast_kernel<<<dim3(DD / 32, FFD / 32), 256, 0, stream>>>(W1 + (size_t)l * DD * FFD, W1T + (size_t)l * FFD * DD, DD, FFD, DD);
    transpose_cast_kernel<<<dim3(FFD / 32, DD / 32), 256, 0, stream>>>(W2 + (size_t)l * FFD * DD, W2T + (size_t)l * DD * FFD, FFD, DD, FFD);
  }
  bias_concat_kernel<<<NLAYER, 256, 0, stream>>>(bq, bk, bv, bqkv);

  for (int pass = 0; pass < 2; ++pass) {
    const int S = pass ? 128 : 256;
    const float* x = pass ? asp : ctx;
    float* acc = pass ? accA : accC;
    const int N = NB * S;

    castpad_kernel<<<N, 256, 0, stream>>>(x, xpad);
    gemm_f16<0, 0><<<dim3(N / 128, DD / 128), 256, 0, stream>>>(xpad, fc1T, fc1_b, tmp, nullptr, KPAD, DD);
    pos_ln_kernel<<<N, 256, 0, stream>>>(tmp, pos, emb_g, emb_b, houtf32, h0f16, S);

    const f16* hin16 = h0f16;
    for (int l = 0; l < NLAYER; ++l) {
      gemm_f16<0, 1><<<dim3(N / 128, (3 * DD) / 128), 256, 0, stream>>>(
          hin16, WqkvT + (size_t)l * 3 * DD * DD, bqkv + l * 3 * DD, nullptr, qkv, DD, 3 * DD);
      if (S == 256) attn_mfma_kernel<256><<<NB * HEADS, 256, 0, stream>>>(qkv, ao);
      else          attn_mfma_kernel<128><<<NB * HEADS, 256, 0, stream>>>(qkv, ao);
      gemm_f16<0, 0><<<dim3(N / 128, DD / 128), 256, 0, stream>>>(
          ao, WoT + (size_t)l * DD * DD, bo + l * DD, tmp, nullptr, DD, DD);
      add_ln_dual<<<N, 256, 0, stream>>>(houtf32, tmp, ln1g + l * DD, ln1b + l * DD, hmf32, hmf16);
      gemm_f16<1, 1><<<dim3(N / 128, FFD / 128), 256, 0, stream>>>(
          hmf16, W1T + (size_t)l * FFD * DD, bf1 + l * FFD, nullptr, mid, DD, FFD);
      gemm_f16<0, 0><<<dim3(N / 128, DD / 128), 256, 0, stream>>>(
          mid, W2T + (size_t)l * DD * FFD, bf2 + l * DD, tmp, nullptr, FFD, DD);
      add_ln_dual<<<N, 256, 0, stream>>>(hmf32, tmp, ln2g + l * DD, ln2b + l * DD, houtf32, outs16[l]);
      hin16 = outs16[l];
    }

    OutsF16 o4;
    for (int i = 0; i < 4; ++i) o4.p[i] = outs16[i];
    invnorm16_kernel<<<N, 256, 0, stream>>>(o4, invn);
    normsum16_kernel<<<dim3(NB, 12), 256, 0, stream>>>(o4, invn, acc, S);
  }

  final_dot_kernel<<<NB, 256, 0, stream>>>(accA, accC, out);
}

// Round 3
// 1175.244 us; speedup vs baseline: 8.7239x; 1.4261x over previous
//
#include <hip/hip_runtime.h>
#include <math.h>

typedef _Float16 f16;
typedef _Float16 h8 __attribute__((ext_vector_type(8)));
typedef float f32x4 __attribute__((ext_vector_type(4)));

#define HEADS 12
#define DH 64
#define DD 768
#define FFD 3072
#define EMBD 300
#define KPAD 320
#define NLAYER 4
#define NB 16
#define NCTX 4096           // 16 * 256
#define NALL 6144           // 16*256 + 16*128

// ---------------- block reduction (sum) ----------------
__device__ __forceinline__ float block_reduce_sum(float v, float* red) {
  #pragma unroll
  for (int o = 32; o; o >>= 1) v += __shfl_xor(v, o);
  const int wid = threadIdx.x >> 6;
  __syncthreads();
  if ((threadIdx.x & 63) == 0) red[wid] = v;
  __syncthreads();
  float r = red[0];
  #pragma unroll
  for (int w = 1; w < 4; ++w) r += red[w];
  return r;
}

// ---------------- async global->LDS 16B ----------------
__device__ __forceinline__ void gload16(const f16* g, f16* lds) {
  __builtin_amdgcn_global_load_lds(
      (const __attribute__((address_space(1))) unsigned int*)g,
      (__attribute__((address_space(3))) unsigned int*)lds, 16, 0, 0);
}

// ---------------- weight transpose + cast (z-batched) ----------------
__launch_bounds__(256)
__global__ void transpose_cast_kernel(const float* __restrict__ W, f16* __restrict__ Wt,
                                      int K, int M, int Kpad,
                                      size_t srcStride, size_t dstStride) {
  W += (size_t)blockIdx.z * srcStride;
  Wt += (size_t)blockIdx.z * dstStride;
  __shared__ float t[32][33];
  const int k0 = blockIdx.x * 32, m0 = blockIdx.y * 32;
  const int c = threadIdx.x & 31, r8 = threadIdx.x >> 5;
  #pragma unroll
  for (int p = 0; p < 4; ++p) {
    const int k = k0 + r8 + p * 8;
    t[r8 + p * 8][c] = (k < K && m0 + c < M) ? W[(size_t)k * M + m0 + c] : 0.f;
  }
  __syncthreads();
  #pragma unroll
  for (int p = 0; p < 4; ++p) {
    const int m = m0 + r8 + p * 8;
    const int k = k0 + c;
    if (m < M && k < Kpad) Wt[(size_t)m * Kpad + k] = (f16)t[c][r8 + p * 8];
  }
}

__launch_bounds__(256)
__global__ void castpad_kernel(const float* __restrict__ ctx, const float* __restrict__ asp,
                               f16* __restrict__ xp) {
  const int tok = blockIdx.x;
  const float* src;
  int r;
  if (tok < NCTX) { src = ctx; r = tok; } else { src = asp; r = tok - NCTX; }
  for (int j = threadIdx.x; j < KPAD; j += 256)
    xp[(size_t)tok * KPAD + j] = (j < EMBD) ? (f16)src[(size_t)r * EMBD + j] : (f16)0.f;
}

__launch_bounds__(256)
__global__ void bias_concat_kernel(const float* __restrict__ bq, const float* __restrict__ bk,
                                   const float* __restrict__ bv, float* __restrict__ bqkv) {
  const int l = blockIdx.x;
  for (int j = threadIdx.x; j < DD; j += 256) {
    bqkv[l * 3 * DD + j] = bq[l * DD + j];
    bqkv[l * 3 * DD + DD + j] = bk[l * DD + j];
    bqkv[l * 3 * DD + 2 * DD + j] = bv[l * DD + j];
  }
}

// ---------------- f16 MFMA GEMM (global_load_lds staging, swizzled linear LDS) ----------------
#define GBM 128
#define GBN 128
#define GBK 32

template<int ACT, int OUTF16>
__launch_bounds__(256)
__global__ void gemm_f16(const f16* __restrict__ A, const f16* __restrict__ Bt,
                         const float* __restrict__ bias,
                         float* __restrict__ C32, f16* __restrict__ C16,
                         int K, int M) {
  __shared__ __align__(16) f16 As[GBM * GBK];
  __shared__ __align__(16) f16 Bs[GBN * GBK];
  const int tid = threadIdx.x;
  const int lane = tid & 63, wid = tid >> 6;
  const int wr = (wid >> 1) * 64, wc = (wid & 1) * 64;
  const int bm = blockIdx.x * GBM, bn = blockIdx.y * GBN;
  const int l15 = lane & 15, lg = lane >> 4;

  // staging: chunk v = wid*128 + c*64 + lane; LDS gets linear v*16B;
  // global source column is XOR-swizzled so the ds_read side is conflict-light.
  const f16* Ar[2]; const f16* Br[2];
  #pragma unroll
  for (int c = 0; c < 2; ++c) {
    const int v = wid * 128 + c * 64 + lane;
    const int row = v >> 2;
    const int col = ((v & 3) ^ ((row >> 1) & 3)) * 8;
    Ar[c] = A + (size_t)(bm + row) * K + col;
    Br[c] = Bt + (size_t)(bn + row) * K + col;
  }
  f16* ldsA[2] = { &As[(wid * 2 + 0) * 512], &As[(wid * 2 + 1) * 512] };
  f16* ldsB[2] = { &Bs[(wid * 2 + 0) * 512], &Bs[(wid * 2 + 1) * 512] };

  const int kx = (lg ^ ((l15 >> 1) & 3)) * 8;  // read-side swizzle (matches source)

  f32x4 acc[4][4] = {};

  for (int k0 = 0; k0 < K; k0 += GBK) {
    gload16(Ar[0] + k0, ldsA[0]);
    gload16(Ar[1] + k0, ldsA[1]);
    gload16(Br[0] + k0, ldsB[0]);
    gload16(Br[1] + k0, ldsB[1]);
    __syncthreads();   // compiler emits vmcnt(0) drain before barrier
    h8 af[4], bf[4];
    #pragma unroll
    for (int m = 0; m < 4; ++m) af[m] = *(const h8*)&As[(wr + m * 16 + l15) * GBK + kx];
    #pragma unroll
    for (int n = 0; n < 4; ++n) bf[n] = *(const h8*)&Bs[(wc + n * 16 + l15) * GBK + kx];
    #pragma unroll
    for (int m = 0; m < 4; ++m)
      #pragma unroll
      for (int n = 0; n < 4; ++n)
        acc[m][n] = __builtin_amdgcn_mfma_f32_16x16x32_f16(af[m], bf[n], acc[m][n], 0, 0, 0);
    __syncthreads();
  }

  #pragma unroll
  for (int m = 0; m < 4; ++m) {
    #pragma unroll
    for (int n = 0; n < 4; ++n) {
      #pragma unroll
      for (int r = 0; r < 4; ++r) {
        const int row = bm + wr + m * 16 + lg * 4 + r;
        const int col = bn + wc + n * 16 + l15;
        float v = acc[m][n][r] + bias[col];
        if (ACT == 1) {
          const float u = 1.5957691216057308f * (v + 0.044715f * v * v * v);
          v = v / (1.f + __expf(-u));
        }
        if (OUTF16) C16[(size_t)row * M + col] = (f16)v;
        else        C32[(size_t)row * M + col] = v;
      }
    }
  }
}

// ---------------- MFMA attention: one block per (b,h) ----------------
template<int S>
__launch_bounds__(256)
__global__ void attn_mfma_kernel(const f16* __restrict__ qkv, f16* __restrict__ ao, int tokoff) {
  constexpr int KSTR = 88;
  constexpr int VSTR = 264;
  __shared__ __align__(16) f16 Ks[S][KSTR];
  __shared__ __align__(16) f16 Vt[DH][VSTR];
  __shared__ __align__(16) f16 Pl[4][16][VSTR];
  const int b = blockIdx.x / HEADS, h = blockIdx.x % HEADS;
  const int tid = threadIdx.x, lane = tid & 63, wid = tid >> 6;
  const int l15 = lane & 15, lg = lane >> 4;
  const size_t base = (size_t)(tokoff + b * S) * (3 * DD) + (size_t)h * DH;
  const f16* qg = qkv + base;
  const f16* kg = qkv + base + DD;
  const f16* vg = qkv + base + 2 * DD;

  for (int c = tid; c < S * 8; c += 256) {
    const int row = c >> 3, off = (c & 7) * 8;
    *(h8*)&Ks[row][off] = *(const h8*)&kg[(size_t)row * (3 * DD) + off];
    const h8 vv = *(const h8*)&vg[(size_t)row * (3 * DD) + off];
    #pragma unroll
    for (int j = 0; j < 8; ++j) Vt[off + j][row] = vv[j];
  }
  __syncthreads();

  for (int qt = wid; qt < S / 16; qt += 4) {
    const int q0 = qt * 16;
    h8 aq[2];
    #pragma unroll
    for (int s = 0; s < 2; ++s)
      aq[s] = *(const h8*)&qg[(size_t)(q0 + l15) * (3 * DD) + s * 32 + lg * 8];

    f32x4 sc[S / 16];
    #pragma unroll
    for (int kt = 0; kt < S / 16; ++kt) {
      f32x4 c = {};
      const h8 b0 = *(const h8*)&Ks[kt * 16 + l15][lg * 8];
      const h8 b1 = *(const h8*)&Ks[kt * 16 + l15][32 + lg * 8];
      c = __builtin_amdgcn_mfma_f32_16x16x32_f16(aq[0], b0, c, 0, 0, 0);
      c = __builtin_amdgcn_mfma_f32_16x16x32_f16(aq[1], b1, c, 0, 0, 0);
      sc[kt] = c;
    }
    float mx[4], zz[4];
    #pragma unroll
    for (int r = 0; r < 4; ++r) {
      float m = -1e30f;
      #pragma unroll
      for (int kt = 0; kt < S / 16; ++kt) m = fmaxf(m, sc[kt][r]);
      #pragma unroll
      for (int o = 1; o < 16; o <<= 1) m = fmaxf(m, __shfl_xor(m, o));
      mx[r] = m; zz[r] = 0.f;
    }
    #pragma unroll
    for (int kt = 0; kt < S / 16; ++kt)
      #pragma unroll
      for (int r = 0; r < 4; ++r) {
        const float p = __expf((sc[kt][r] - mx[r]) * 0.125f);
        zz[r] += p;
        Pl[wid][lg * 4 + r][kt * 16 + l15] = (f16)p;
      }
    #pragma unroll
    for (int r = 0; r < 4; ++r) {
      #pragma unroll
      for (int o = 1; o < 16; o <<= 1) zz[r] += __shfl_xor(zz[r], o);
      zz[r] = 1.f / zz[r];
    }
    // Pl is wave-private; same-wave LDS ordering makes barriers unnecessary here.
    f32x4 o4[4] = {};
    #pragma unroll
    for (int ks = 0; ks < S / 32; ++ks) {
      const h8 pa = *(const h8*)&Pl[wid][l15][ks * 32 + lg * 8];
      #pragma unroll
      for (int n = 0; n < 4; ++n) {
        const h8 bv_ = *(const h8*)&Vt[n * 16 + l15][ks * 32 + lg * 8];
        o4[n] = __builtin_amdgcn_mfma_f32_16x16x32_f16(pa, bv_, o4[n], 0, 0, 0);
      }
    }
    #pragma unroll
    for (int n = 0; n < 4; ++n)
      #pragma unroll
      for (int r = 0; r < 4; ++r) {
        const int row = q0 + lg * 4 + r;
        ao[(size_t)(tokoff + b * S + row) * DD + h * DH + n * 16 + l15] = (f16)(o4[n][r] * zz[r]);
      }
  }
}

// ---------------- fc1-out + pos_emb + LN -> f32 + f16 ----------------
__launch_bounds__(256)
__global__ void pos_ln_kernel(const float* __restrict__ tmp, const float* __restrict__ pos,
                              const float* __restrict__ g, const float* __restrict__ be,
                              float* __restrict__ of32, f16* __restrict__ of16) {
  __shared__ float red[4];
  const int tok = blockIdx.x;
  const int s = (tok < NCTX) ? (tok & 255) : (tok & 127);
  const size_t row = (size_t)tok * DD;
  float x[3]; float sm = 0.f, ss = 0.f;
  #pragma unroll
  for (int i = 0; i < 3; ++i) {
    const int j = threadIdx.x + (i << 8);
    x[i] = tmp[row + j] + pos[(size_t)s * DD + j];
    sm += x[i]; ss += x[i] * x[i];
  }
  sm = block_reduce_sum(sm, red);
  ss = block_reduce_sum(ss, red);
  const float mean = sm * (1.f / DD);
  const float inv = rsqrtf(ss * (1.f / DD) - mean * mean + 1e-12f);
  #pragma unroll
  for (int i = 0; i < 3; ++i) {
    const int j = threadIdx.x + (i << 8);
    const float v = (x[i] - mean) * inv * g[j] + be[j];
    of32[row + j] = v;
    of16[row + j] = (f16)v;
  }
}

// ---------------- residual add + LN -> f32 + f16 ----------------
__launch_bounds__(256)
__global__ void add_ln_dual(const float* __restrict__ hin, const float* __restrict__ dlt,
                            const float* __restrict__ g, const float* __restrict__ be,
                            float* __restrict__ of32, f16* __restrict__ of16) {
  __shared__ float red[4];
  const size_t row = (size_t)blockIdx.x * DD;
  float x[3]; float sm = 0.f, ss = 0.f;
  #pragma unroll
  for (int i = 0; i < 3; ++i) {
    const int j = threadIdx.x + (i << 8);
    x[i] = hin[row + j] + dlt[row + j];
    sm += x[i]; ss += x[i] * x[i];
  }
  sm = block_reduce_sum(sm, red);
  ss = block_reduce_sum(ss, red);
  const float mean = sm * (1.f / DD);
  const float inv = rsqrtf(ss * (1.f / DD) - mean * mean + 1e-12f);
  #pragma unroll
  for (int i = 0; i < 3; ++i) {
    const int j = threadIdx.x + (i << 8);
    const float v = (x[i] - mean) * inv * g[j] + be[j];
    of32[row + j] = v;
    of16[row + j] = (f16)v;
  }
}

// ---------------- final cosine reduction ----------------
struct OutsF16 { const f16* p[4]; };

__launch_bounds__(256)
__global__ void invnorm16_kernel(OutsF16 o4, float* __restrict__ invn) {
  __shared__ float red[4];
  const size_t row = (size_t)blockIdx.x * DD;
  float ss = 0.f;
  #pragma unroll
  for (int l = 0; l < 4; ++l)
    #pragma unroll
    for (int i = 0; i < 3; ++i) {
      const float v = (float)o4.p[l][row + threadIdx.x + (i << 8)];
      ss += v * v;
    }
  ss = block_reduce_sum(ss, red);
  if (threadIdx.x == 0) invn[blockIdx.x] = 1.f / fmaxf(sqrtf(ss), 1e-8f);
}

__launch_bounds__(256)
__global__ void normsum16_kernel(OutsF16 o4, const float* __restrict__ invn,
                                 float* __restrict__ accC, float* __restrict__ accA) {
  const int b = blockIdx.x;
  const int l = blockIdx.y / 3;
  const int j = (blockIdx.y % 3) * 256 + threadIdx.x;
  const int pass = blockIdx.z;
  const int S = pass ? 128 : 256;
  const int tb = pass ? (NCTX + b * 128) : (b * 256);
  float* acc = pass ? accA : accC;
  const f16* __restrict__ src = o4.p[l];
  float s = 0.f;
  for (int si = 0; si < S; ++si)
    s = fmaf((float)src[(size_t)(tb + si) * DD + j], invn[tb + si], s);
  acc[(size_t)b * (4 * DD) + (size_t)l * DD + j] = s;
}

__launch_bounds__(256)
__global__ void final_dot_kernel(const float* __restrict__ a, const float* __restrict__ c,
                                 float* __restrict__ out) {
  __shared__ float red[4];
  const size_t base = (size_t)blockIdx.x * (4 * DD);
  float s = 0.f;
  #pragma unroll
  for (int i = 0; i < 12; ++i) {
    const int j = threadIdx.x + (i << 8);
    s = fmaf(a[base + j], c[base + j], s);
  }
  s = block_reduce_sum(s, red);
  if (threadIdx.x == 0) out[blockIdx.x] = s;
}

// ---------------- host orchestration ----------------
extern "C" void kernel_launch(void* const* d_in, const int* in_sizes, int n_in,
                              void* d_out, int out_size, void* d_ws, size_t ws_size,
                              hipStream_t stream) {
  (void)in_sizes; (void)n_in; (void)out_size; (void)ws_size;
  const float* ctx   = (const float*)d_in[0];
  const float* asp   = (const float*)d_in[1];
  const float* fc1_w = (const float*)d_in[2];
  const float* fc1_b = (const float*)d_in[3];
  const float* pos   = (const float*)d_in[4];
  const float* emb_g = (const float*)d_in[5];
  const float* emb_b = (const float*)d_in[6];
  const float* Wq    = (const float*)d_in[7];
  const float* bq    = (const float*)d_in[8];
  const float* Wk    = (const float*)d_in[9];
  const float* bk    = (const float*)d_in[10];
  const float* Wv    = (const float*)d_in[11];
  const float* bv    = (const float*)d_in[12];
  const float* Wo    = (const float*)d_in[13];
  const float* bo    = (const float*)d_in[14];
  const float* ln1g  = (const float*)d_in[15];
  const float* ln1b  = (const float*)d_in[16];
  const float* W1    = (const float*)d_in[17];
  const float* bf1   = (const float*)d_in[18];
  const float* W2    = (const float*)d_in[19];
  const float* bf2   = (const float*)d_in[20];
  const float* ln2g  = (const float*)d_in[21];
  const float* ln2b  = (const float*)d_in[22];
  float* out = (float*)d_out;

  // ---- workspace carving ----
  f16* f = (f16*)d_ws;
  size_t o = 0;
  f16* fc1T  = f + o; o += (size_t)DD * KPAD;
  f16* WqkvT = f + o; o += (size_t)NLAYER * 3 * DD * DD;
  f16* WoT   = f + o; o += (size_t)NLAYER * DD * DD;
  f16* W1T   = f + o; o += (size_t)NLAYER * FFD * DD;
  f16* W2T   = f + o; o += (size_t)NLAYER * DD * FFD;
  f16* R     = f + o; o += (size_t)NALL * FFD;     // alias: xpad | qkv+ao | mid
  f16* h0f16 = f + o; o += (size_t)NALL * DD;
  f16* hmf16 = f + o; o += (size_t)NALL * DD;
  f16* outs16[4];
  for (int l = 0; l < 4; ++l) { outs16[l] = f + o; o += (size_t)NALL * DD; }

  f16* xpad = R;
  f16* qkv  = R;
  f16* ao   = R + (size_t)NALL * 3 * DD;
  f16* mid  = R;

  float* g32 = (float*)(f + o);
  size_t o2 = 0;
  float* tmp     = g32 + o2; o2 += (size_t)NALL * DD;
  float* hmf32   = g32 + o2; o2 += (size_t)NALL * DD;
  float* houtf32 = g32 + o2; o2 += (size_t)NALL * DD;
  float* bqkv    = g32 + o2; o2 += (size_t)NLAYER * 3 * DD;
  float* accC    = g32 + o2; o2 += (size_t)NB * 4 * DD;
  float* accA    = g32 + o2; o2 += (size_t)NB * 4 * DD;
  float* invn    = g32 + o2; o2 += NALL;

  // ---- weight prep (z-batched) ----
  transpose_cast_kernel<<<dim3(KPAD / 32, DD / 32, 1), 256, 0, stream>>>(
      fc1_w, fc1T, EMBD, DD, KPAD, 0, 0);
  transpose_cast_kernel<<<dim3(DD / 32, DD / 32, NLAYER), 256, 0, stream>>>(
      Wq, WqkvT, DD, DD, DD, (size_t)DD * DD, (size_t)3 * DD * DD);
  transpose_cast_kernel<<<dim3(DD / 32, DD / 32, NLAYER), 256, 0, stream>>>(
      Wk, WqkvT + (size_t)DD * DD, DD, DD, DD, (size_t)DD * DD, (size_t)3 * DD * DD);
  transpose_cast_kernel<<<dim3(DD / 32, DD / 32, NLAYER), 256, 0, stream>>>(
      Wv, WqkvT + (size_t)2 * DD * DD, DD, DD, DD, (size_t)DD * DD, (size_t)3 * DD * DD);
  transpose_cast_kernel<<<dim3(DD / 32, DD / 32, NLAYER), 256, 0, stream>>>(
      Wo, WoT, DD, DD, DD, (size_t)DD * DD, (size_t)DD * DD);
  transpose_cast_kernel<<<dim3(DD / 32, FFD / 32, NLAYER), 256, 0, stream>>>(
      W1, W1T, DD, FFD, DD, (size_t)DD * FFD, (size_t)FFD * DD);
  transpose_cast_kernel<<<dim3(FFD / 32, DD / 32, NLAYER), 256, 0, stream>>>(
      W2, W2T, FFD, DD, FFD, (size_t)FFD * DD, (size_t)DD * FFD);
  bias_concat_kernel<<<NLAYER, 256, 0, stream>>>(bq, bk, bv, bqkv);

  // ---- merged encoder over 6144 tokens ----
  castpad_kernel<<<NALL, 256, 0, stream>>>(ctx, asp, xpad);
  gemm_f16<0, 0><<<dim3(NALL / 128, DD / 128), 256, 0, stream>>>(
      xpad, fc1T, fc1_b, tmp, nullptr, KPAD, DD);
  pos_ln_kernel<<<NALL, 256, 0, stream>>>(tmp, pos, emb_g, emb_b, houtf32, h0f16);

  const f16* hin16 = h0f16;
  for (int l = 0; l < NLAYER; ++l) {
    gemm_f16<0, 1><<<dim3(NALL / 128, (3 * DD) / 128), 256, 0, stream>>>(
        hin16, WqkvT + (size_t)l * 3 * DD * DD, bqkv + l * 3 * DD, nullptr, qkv, DD, 3 * DD);
    attn_mfma_kernel<256><<<NB * HEADS, 256, 0, stream>>>(qkv, ao, 0);
    attn_mfma_kernel<128><<<NB * HEADS, 256, 0, stream>>>(qkv, ao, NCTX);
    gemm_f16<0, 0><<<dim3(NALL / 128, DD / 128), 256, 0, stream>>>(
        ao, WoT + (size_t)l * DD * DD, bo + l * DD, tmp, nullptr, DD, DD);
    add_ln_dual<<<NALL, 256, 0, stream>>>(houtf32, tmp, ln1g + l * DD, ln1b + l * DD, hmf32, hmf16);
    gemm_f16<1, 1><<<dim3(NALL / 128, FFD / 128), 256, 0, stream>>>(
        hmf16, W1T + (size_t)l * FFD * DD, bf1 + l * FFD, nullptr, mid, DD, FFD);
    gemm_f16<0, 0><<<dim3(NALL / 128, DD / 128), 256, 0, stream>>>(
        mid, W2T + (size_t)l * DD * FFD, bf2 + l * DD, tmp, nullptr, FFD, DD);
    add_ln_dual<<<NALL, 256, 0, stream>>>(hmf32, tmp, ln2g + l * DD, ln2b + l * DD, houtf32, outs16[l]);
    hin16 = outs16[l];
  }

  OutsF16 o4;
  for (int i = 0; i < 4; ++i) o4.p[i] = outs16[i];
  invnorm16_kernel<<<NALL, 256, 0, stream>>>(o4, invn);
  normsum16_kernel<<<dim3(NB, 12, 2), 256, 0, stream>>>(o4, invn, accC, accA);
  final_dot_kernel<<<NB, 256, 0, stream>>>(accA, accC, out);
}